// Round 6
// baseline (712.820 us; speedup 1.0000x reference)
//
#include <hip/hip_runtime.h>
#include <cmath>

#define NNODES 20000
#define NEDGES 640000
#define DDIM   128
#define TN     16
#define BE     64                 // edges per tile
#define NTILES (NEDGES / BE)      // 10000
#define NBLK   512                // persistent blocks (~2/CU)

typedef __attribute__((ext_vector_type(8))) short bf16x8;
typedef __attribute__((ext_vector_type(4))) float f32x4;

__device__ __forceinline__ unsigned short f2bf(float x) {
    union { float f; unsigned u; } v; v.f = x;
    unsigned r = v.u + 0x7FFFu + ((v.u >> 16) & 1u);   // RNE
    return (unsigned short)(r >> 16);
}
// packed bf16 pair: D[15:0]=bf16(lo), D[31:16]=bf16(hi)
__device__ __forceinline__ unsigned cvtpk(float lo, float hi) {
    unsigned r;
    asm("v_cvt_pk_bf16_f32 %0, %1, %2" : "=v"(r) : "v"(lo), "v"(hi));
    return r;
}
// Barrier WITHOUT vmcnt drain (unlike __syncthreads): LDS-visibility only.
// Keeps prefetch global loads in flight across the barrier (T4 discipline).
__device__ __forceinline__ void BAR() {
    asm volatile("s_waitcnt lgkmcnt(0)\n\ts_barrier" ::: "memory");
}

// ---------------------------------------------------------------------------
// Pack fp32 weight matrix [K x 128] into bf16 MFMA A-fragment layout.
// frame f = kt*8 + nt; elem (lane,i): W[kt*32 + (lane>>4)*8 + i][nt*16 + (lane&15)]
// ---------------------------------------------------------------------------
__global__ void pack_weights(const float* __restrict__ W, unsigned short* __restrict__ dst)
{
    const int f  = blockIdx.x;
    const int kt = f >> 3, nt = f & 7;
    const int t  = threadIdx.x;
#pragma unroll
    for (int ii = 0; ii < 2; ii++) {
        const int idx  = t * 2 + ii;          // 0..511
        const int lane = idx >> 3, i = idx & 7;
        const int k = kt * 32 + (lane >> 4) * 8 + i;
        const int n = nt * 16 + (lane & 15);
        dst[f * 512 + idx] = f2bf(W[k * 128 + n]);
    }
}

// ---------------------------------------------------------------------------
// q = node_feats @ Wq, k = node_feats @ Wk  (fp32)
// ---------------------------------------------------------------------------
__global__ __launch_bounds__(256) void qk_proj_kernel(
    const float* __restrict__ nf, const float* __restrict__ Wq,
    const float* __restrict__ Wk, float* __restrict__ qbuf,
    float* __restrict__ kbuf)
{
    __shared__ float s_nf[TN * DDIM];
    const int t  = threadIdx.x;
    const int n0 = blockIdx.x * TN;
    {
        const float4* src = (const float4*)(nf + (size_t)n0 * DDIM);
        float4* dst = (float4*)s_nf;
        for (int i = t; i < TN * DDIM / 4; i += 256) dst[i] = src[i];
    }
    __syncthreads();

    const int j = t & 127;
    const float* W = (t < 128) ? Wq : Wk;
    float acc[TN];
#pragma unroll
    for (int n = 0; n < TN; n++) acc[n] = 0.f;

    for (int k = 0; k < DDIM; k += 4) {
        const float w0 = W[(k + 0) * DDIM + j];
        const float w1 = W[(k + 1) * DDIM + j];
        const float w2 = W[(k + 2) * DDIM + j];
        const float w3 = W[(k + 3) * DDIM + j];
#pragma unroll
        for (int n = 0; n < TN; n++) {
            const float4 f = *(const float4*)&s_nf[n * DDIM + k];
            acc[n] = fmaf(f.w, w3, fmaf(f.z, w2, fmaf(f.y, w1, fmaf(f.x, w0, acc[n]))));
        }
    }
    float* outp = (t < 128) ? qbuf : kbuf;
    for (int n = 0; n < TN; n++) outp[(size_t)(n0 + n) * DDIM + j] = acc[n];
}

// ---------------------------------------------------------------------------
// Persistent fused edge kernel, software-pipelined over 64-edge tiles.
// 4 waves/block, wave w = head w. Per tile:
//   B-top: issue t+1 q/k gathers (idx preloaded last tile), idx(t+2), sh/rv(t)
//   MLP (2 paths, MFMA)  -> acc2
//   C: issue t+1 ef/chi loads; attention from prod regs; s_alpha
//   D: scatter atomics
//   E: prod(t+1) = q*k; cvt+ds_write s_a(t+1)
// All barriers are lgkm-only (no vmcnt drain).
// ---------------------------------------------------------------------------
__global__ __launch_bounds__(256, 2) void edge_kernel(
    const float* __restrict__ edge_sh, const float* __restrict__ cutoffs,
    const int* __restrict__ senders, const int* __restrict__ receivers,
    const float* __restrict__ edge_feats, const float* __restrict__ chi_scalar,
    const unsigned short* __restrict__ w1r, const unsigned short* __restrict__ w1s,
    const unsigned short* __restrict__ w2r, const unsigned short* __restrict__ w2s,
    const float* __restrict__ b_rad1, const float* __restrict__ b_sph1,
    const float* __restrict__ b_rad2, const float* __restrict__ b_sph2,
    const float* __restrict__ qbuf, const float* __restrict__ kbuf,
    float* __restrict__ out)
{
    __shared__ unsigned short s_a[2 * 64 * 64];   // 16 KB [path][edge][k] swizzled
    __shared__ unsigned short s_h[64 * 128];      // 16 KB [edge][hid] swizzled
    __shared__ float s_alpha[64][4];              // 1 KB
    char* pa = (char*)s_a;
    char* ph = (char*)s_h;

    const int t  = threadIdx.x;
    const int w  = t >> 6;        // wave id == head id
    const int l  = t & 63;
    const int el = l & 15;
    const int c0base = w * 32 + (l >> 4) * 4;

    int tile = blockIdx.x;

    // ---- loop-invariant bias preloads ----
    f32x4 b2s[2];
#pragma unroll
    for (int ct = 0; ct < 2; ct++) {
        const float4 br = *(const float4*)(b_rad2 + c0base + ct * 16);
        const float4 bs = *(const float4*)(b_sph2 + c0base + ct * 16);
        b2s[ct] = (f32x4){ br.x + bs.x, br.y + bs.y, br.z + bs.z, br.w + bs.w };
    }
    float4 b1v[2][2];
#pragma unroll
    for (int ht = 0; ht < 2; ht++) {
        const int hid0 = w * 32 + ht * 16 + (l >> 4) * 4;
        b1v[0][ht] = *(const float4*)(b_rad1 + hid0);
        b1v[1][ht] = *(const float4*)(b_sph1 + hid0);
    }

    // ---- prologue: first tile ----
    float cutC[4], cutN[4], cutP[4];
    int rnN[4], snN[4];
    f32x4 qraw[2][4], kraw[2][4];
    {
        int rn0[4], sn0[4];
#pragma unroll
        for (int et = 0; et < 4; et++) {
            const int eg = tile * BE + et * 16 + el;
            rn0[et] = receivers[eg]; sn0[et] = senders[eg]; cutC[et] = cutoffs[eg];
        }
#pragma unroll
        for (int et = 0; et < 4; et++)
#pragma unroll
            for (int ct = 0; ct < 2; ct++) {
                const float4 qv = *(const float4*)(qbuf + (size_t)rn0[et] * 128 + c0base + ct * 16);
                const float4 kv = *(const float4*)(kbuf + (size_t)sn0[et] * 128 + c0base + ct * 16);
                qraw[ct][et] = (f32x4){ qv.x, qv.y, qv.z, qv.w };
                kraw[ct][et] = (f32x4){ kv.x, kv.y, kv.z, kv.w };
            }
        if (tile + NBLK < NTILES) {
#pragma unroll
            for (int et = 0; et < 4; et++) {
                const int eg = (tile + NBLK) * BE + et * 16 + el;
                rnN[et] = receivers[eg]; snN[et] = senders[eg]; cutN[et] = cutoffs[eg];
            }
        }
#pragma unroll
        for (int ii = 0; ii < 4; ii++) {
            const int idx = t + ii * 256;
            const int r = idx >> 4, c4 = idx & 15;
            const float4 a = *(const float4*)(edge_feats + (size_t)(tile * BE + r) * 64 + c4 * 4);
            const float4 b = *(const float4*)(chi_scalar + (size_t)(tile * BE + r) * 64 + c4 * 4);
            const uint2 av = { cvtpk(a.x, a.y), cvtpk(a.z, a.w) };
            const uint2 bv = { cvtpk(b.x, b.y), cvtpk(b.z, b.w) };
            const int off = (r * 128 + c4 * 8) ^ ((r & 7) << 4);
            *(uint2*)(pa + off)        = av;
            *(uint2*)(pa + 8192 + off) = bv;
        }
        BAR();
    }
    f32x4 prod[2][4];
#pragma unroll
    for (int ct = 0; ct < 2; ct++)
#pragma unroll
        for (int et = 0; et < 4; et++)
            prod[ct][et] = qraw[ct][et] * kraw[ct][et];

    float4 efr[4], chr[4];

    for (;;) {
        const int next = tile + NBLK;
        const bool have_next = (next < NTILES);

        // ---- B-top: issue next-tile gathers (idx already resident) ----
        if (have_next) {
#pragma unroll
            for (int et = 0; et < 4; et++)
#pragma unroll
                for (int ct = 0; ct < 2; ct++) {
                    const float4 qv = *(const float4*)(qbuf + (size_t)rnN[et] * 128 + c0base + ct * 16);
                    const float4 kv = *(const float4*)(kbuf + (size_t)snN[et] * 128 + c0base + ct * 16);
                    qraw[ct][et] = (f32x4){ qv.x, qv.y, qv.z, qv.w };
                    kraw[ct][et] = (f32x4){ kv.x, kv.y, kv.z, kv.w };
                }
        }
#pragma unroll
        for (int et = 0; et < 4; et++) cutP[et] = cutN[et];
        if (next + NBLK < NTILES) {
#pragma unroll
            for (int et = 0; et < 4; et++) {
                const int eg = (next + NBLK) * BE + et * 16 + el;
                rnN[et] = receivers[eg]; snN[et] = senders[eg]; cutN[et] = cutoffs[eg];
            }
        }
        const int se = tile * BE + (t >> 2);
        const int rvS = receivers[se];
        const float4 shS = *(const float4*)(edge_sh + (size_t)se * 16 + (t & 3) * 4);

        // ---- MLP ----
        f32x4 acc2[2][4];
#pragma unroll
        for (int ct = 0; ct < 2; ct++)
#pragma unroll
            for (int et = 0; et < 4; et++)
                acc2[ct][et] = (f32x4){0.f, 0.f, 0.f, 0.f};

#pragma unroll
        for (int path = 0; path < 2; path++) {
            const unsigned short* W1p = path ? w1s : w1r;
            const unsigned short* W2p = path ? w2s : w2r;
            const char* ab = pa + path * 8192;

            f32x4 acc1[2][4];
#pragma unroll
            for (int ht = 0; ht < 2; ht++)
#pragma unroll
                for (int et = 0; et < 4; et++)
                    acc1[ht][et] = (f32x4){0.f, 0.f, 0.f, 0.f};

#pragma unroll
            for (int kt = 0; kt < 2; kt++) {
                bf16x8 bfrag[4];
#pragma unroll
                for (int et = 0; et < 4; et++) {
                    const int e = et * 16 + el;
                    const int k = kt * 32 + (l >> 4) * 8;
                    bfrag[et] = *(const bf16x8*)(ab + ((e * 128 + k * 2) ^ ((e & 7) << 4)));
                }
#pragma unroll
                for (int ht = 0; ht < 2; ht++) {
                    const bf16x8 afrag = *(const bf16x8*)(W1p + (size_t)(kt * 8 + w * 2 + ht) * 512 + l * 8);
#pragma unroll
                    for (int et = 0; et < 4; et++)
                        acc1[ht][et] = __builtin_amdgcn_mfma_f32_16x16x32_bf16(
                            afrag, bfrag[et], acc1[ht][et], 0, 0, 0);
                }
            }

            // bias + silu -> H
#pragma unroll
            for (int ht = 0; ht < 2; ht++) {
                const int hid0 = w * 32 + ht * 16 + (l >> 4) * 4;
                const float* bvf = (const float*)&b1v[path][ht];
#pragma unroll
                for (int et = 0; et < 4; et++) {
                    const int e = et * 16 + el;
                    float s[4];
#pragma unroll
                    for (int r = 0; r < 4; r++) {
                        const float v = acc1[ht][et][r] + bvf[r];
                        s[r] = v * __builtin_amdgcn_rcpf(1.0f + __expf(-v));
                    }
                    const uint2 hv = { cvtpk(s[0], s[1]), cvtpk(s[2], s[3]) };
                    *(uint2*)(ph + ((e * 256 + hid0 * 2) ^ ((e & 7) << 4))) = hv;
                }
            }
            BAR();

            // Layer 2: acc2 += W2 @ H  (K = 128)
#pragma unroll
            for (int kt = 0; kt < 4; kt++) {
                bf16x8 hfrag[4];
#pragma unroll
                for (int et = 0; et < 4; et++) {
                    const int e = et * 16 + el;
                    const int k = kt * 32 + (l >> 4) * 8;
                    hfrag[et] = *(const bf16x8*)(ph + ((e * 256 + k * 2) ^ ((e & 7) << 4)));
                }
#pragma unroll
                for (int ct = 0; ct < 2; ct++) {
                    const bf16x8 afrag = *(const bf16x8*)(W2p + (size_t)(kt * 8 + w * 2 + ct) * 512 + l * 8);
#pragma unroll
                    for (int et = 0; et < 4; et++)
                        acc2[ct][et] = __builtin_amdgcn_mfma_f32_16x16x32_bf16(
                            afrag, hfrag[et], acc2[ct][et], 0, 0, 0);
                }
            }
            if (path == 0) BAR();   // before path1 overwrites s_h
        }

        // ---- C: issue next ef/chi loads, then attention ----
        if (have_next) {
#pragma unroll
            for (int ii = 0; ii < 4; ii++) {
                const int idx = t + ii * 256;
                const int r = idx >> 4, c4 = idx & 15;
                efr[ii] = *(const float4*)(edge_feats + (size_t)(next * BE + r) * 64 + c4 * 4);
                chr[ii] = *(const float4*)(chi_scalar + (size_t)(next * BE + r) * 64 + c4 * 4);
            }
        }
#pragma unroll
        for (int et = 0; et < 4; et++) {
            float vsum = 0.f;
#pragma unroll
            for (int ct = 0; ct < 2; ct++)
#pragma unroll
                for (int r = 0; r < 4; r++)
                    vsum = fmaf(prod[ct][et][r], acc2[ct][et][r] + b2s[ct][r], vsum);
            vsum += __shfl_xor(vsum, 16, 64);
            vsum += __shfl_xor(vsum, 32, 64);
            if (l < 16) {
                // 1/sqrt(32) * 1/32
                s_alpha[et * 16 + l][w] = vsum * cutC[et] * 0.005524271728019903f;
            }
        }
        BAR();

        // ---- D: coalesced scatter ----
        {
            const float* shf = (const float*)&shS;
#pragma unroll
            for (int j = 0; j < 4; j++) {
                const int comp = (t & 3) * 4 + j;
                const int head = (comp == 0) ? 0 : (comp < 4) ? 1 : (comp < 9) ? 2 : 3;
                atomicAdd(&out[(size_t)rvS * 16 + comp], shf[j] * s_alpha[t >> 2][head]);
            }
        }

        if (!have_next) break;

        // ---- E: finish next-tile staging (waits land here, fully hidden) ----
#pragma unroll
        for (int ct = 0; ct < 2; ct++)
#pragma unroll
            for (int et = 0; et < 4; et++)
                prod[ct][et] = qraw[ct][et] * kraw[ct][et];
#pragma unroll
        for (int ii = 0; ii < 4; ii++) {
            const int idx = t + ii * 256;
            const int r = idx >> 4, c4 = idx & 15;
            const uint2 av = { cvtpk(efr[ii].x, efr[ii].y), cvtpk(efr[ii].z, efr[ii].w) };
            const uint2 bv = { cvtpk(chr[ii].x, chr[ii].y), cvtpk(chr[ii].z, chr[ii].w) };
            const int off = (r * 128 + c4 * 8) ^ ((r & 7) << 4);
            *(uint2*)(pa + off)        = av;
            *(uint2*)(pa + 8192 + off) = bv;
        }
#pragma unroll
        for (int et = 0; et < 4; et++) cutC[et] = cutP[et];
        BAR();
        tile = next;
    }
}

// ---------------------------------------------------------------------------
extern "C" void kernel_launch(void* const* d_in, const int* in_sizes, int n_in,
                              void* d_out, int out_size, void* d_ws, size_t ws_size,
                              hipStream_t stream)
{
    const float* edge_sh    = (const float*)d_in[0];
    const float* node_feats = (const float*)d_in[1];
    const float* edge_feats = (const float*)d_in[2];
    const float* chi_scalar = (const float*)d_in[3];
    const float* cutoffs    = (const float*)d_in[4];
    const int*   senders    = (const int*)d_in[5];
    const int*   receivers  = (const int*)d_in[6];
    const float* W_rad1 = (const float*)d_in[7];
    const float* b_rad1 = (const float*)d_in[8];
    const float* W_rad2 = (const float*)d_in[9];
    const float* b_rad2 = (const float*)d_in[10];
    const float* W_sph1 = (const float*)d_in[11];
    const float* b_sph1 = (const float*)d_in[12];
    const float* W_sph2 = (const float*)d_in[13];
    const float* b_sph2 = (const float*)d_in[14];
    const float* Wq     = (const float*)d_in[15];
    const float* Wk     = (const float*)d_in[16];

    float* out  = (float*)d_out;
    float* qbuf = (float*)d_ws;                          // [N,128] fp32
    float* kbuf = qbuf + (size_t)NNODES * DDIM;          // [N,128] fp32
    unsigned short* w1r = (unsigned short*)(kbuf + (size_t)NNODES * DDIM);
    unsigned short* w1s = w1r + 16 * 512;
    unsigned short* w2r = w1s + 16 * 512;
    unsigned short* w2s = w2r + 32 * 512;

    hipMemsetAsync(out, 0, (size_t)out_size * sizeof(float), stream);

    pack_weights<<<16, 256, 0, stream>>>(W_rad1, w1r);
    pack_weights<<<16, 256, 0, stream>>>(W_sph1, w1s);
    pack_weights<<<32, 256, 0, stream>>>(W_rad2, w2r);
    pack_weights<<<32, 256, 0, stream>>>(W_sph2, w2s);

    qk_proj_kernel<<<NNODES / TN, 256, 0, stream>>>(node_feats, Wq, Wk, qbuf, kbuf);

    edge_kernel<<<NBLK, 256, 0, stream>>>(
        edge_sh, cutoffs, senders, receivers, edge_feats, chi_scalar,
        w1r, w1s, w2r, w2s, b_rad1, b_sph1, b_rad2, b_sph2,
        qbuf, kbuf, out);
}

// Round 7
// 290.290 us; speedup vs baseline: 2.4555x; 2.4555x over previous
//
#include <hip/hip_runtime.h>
#include <cmath>

#define NNODES 20000
#define NEDGES 640000
#define DDIM   128
#define TN     16    // nodes per block in qk kernel
#define BE     64    // edges per block in edge kernel

typedef __attribute__((ext_vector_type(8))) short bf16x8;
typedef __attribute__((ext_vector_type(4))) float f32x4;
typedef __attribute__((ext_vector_type(4))) unsigned short us4;

__device__ __forceinline__ unsigned short f2bf(float x) {
    union { float f; unsigned u; } v; v.f = x;
    unsigned r = v.u + 0x7FFFu + ((v.u >> 16) & 1u);   // RNE
    return (unsigned short)(r >> 16);
}
__device__ __forceinline__ float bf2f(unsigned short h) {
    union { unsigned u; float f; } v; v.u = ((unsigned)h) << 16; return v.f;
}
// packed bf16 pair via HW instruction: D[15:0]=bf16(lo), D[31:16]=bf16(hi)
__device__ __forceinline__ unsigned cvtpk(float lo, float hi) {
    unsigned r;
    asm("v_cvt_pk_bf16_f32 %0, %1, %2" : "=v"(r) : "v"(lo), "v"(hi));
    return r;
}

// ---------------------------------------------------------------------------
// Pack fp32 weight matrix [K x 128] into bf16 MFMA A-fragment layout.
// frame f = kt*8 + nt; elem (lane,i): W[kt*32 + (lane>>4)*8 + i][nt*16 + (lane&15)]
// ---------------------------------------------------------------------------
__global__ void pack_weights(const float* __restrict__ W, unsigned short* __restrict__ dst)
{
    const int f  = blockIdx.x;
    const int kt = f >> 3, nt = f & 7;
    const int t  = threadIdx.x;
#pragma unroll
    for (int ii = 0; ii < 2; ii++) {
        const int idx  = t * 2 + ii;          // 0..511
        const int lane = idx >> 3, i = idx & 7;
        const int k = kt * 32 + (lane >> 4) * 8 + i;
        const int n = nt * 16 + (lane & 15);
        dst[f * 512 + idx] = f2bf(W[k * 128 + n]);
    }
}

// ---------------------------------------------------------------------------
// q = node_feats @ Wq, k = node_feats @ Wk  -> bf16 [N,128] each.
// bf16 storage halves the edge kernel's scattered-gather traffic.
// ---------------------------------------------------------------------------
__global__ __launch_bounds__(256) void qk_proj_kernel(
    const float* __restrict__ nf, const float* __restrict__ Wq,
    const float* __restrict__ Wk, unsigned short* __restrict__ qbuf,
    unsigned short* __restrict__ kbuf)
{
    __shared__ float s_nf[TN * DDIM];
    const int t  = threadIdx.x;
    const int n0 = blockIdx.x * TN;
    {
        const float4* src = (const float4*)(nf + (size_t)n0 * DDIM);
        float4* dst = (float4*)s_nf;
        for (int i = t; i < TN * DDIM / 4; i += 256) dst[i] = src[i];
    }
    __syncthreads();

    const int j = t & 127;
    const float* W = (t < 128) ? Wq : Wk;
    float acc[TN];
#pragma unroll
    for (int n = 0; n < TN; n++) acc[n] = 0.f;

    for (int k = 0; k < DDIM; k += 4) {
        const float w0 = W[(k + 0) * DDIM + j];
        const float w1 = W[(k + 1) * DDIM + j];
        const float w2 = W[(k + 2) * DDIM + j];
        const float w3 = W[(k + 3) * DDIM + j];
#pragma unroll
        for (int n = 0; n < TN; n++) {
            const float4 f = *(const float4*)&s_nf[n * DDIM + k];
            acc[n] = fmaf(f.w, w3, fmaf(f.z, w2, fmaf(f.y, w1, fmaf(f.x, w0, acc[n]))));
        }
    }
    unsigned short* outp = (t < 128) ? qbuf : kbuf;
    for (int n = 0; n < TN; n++) outp[(size_t)(n0 + n) * DDIM + j] = f2bf(acc[n]);
}

// ---------------------------------------------------------------------------
// Fused edge kernel (round-2 skeleton). 64 edges/block, 4 waves, wave = head.
// mfma(W_frag(A), edge_frag(B)) -> C frag: lane = edge (l&15 of tile),
// cols (l>>4)*4 + reg (+16 per col-tile).
// ---------------------------------------------------------------------------
__global__ __launch_bounds__(256) void edge_kernel(
    const float* __restrict__ edge_sh, const float* __restrict__ cutoffs,
    const int* __restrict__ senders, const int* __restrict__ receivers,
    const float* __restrict__ edge_feats, const float* __restrict__ chi_scalar,
    const unsigned short* __restrict__ w1r, const unsigned short* __restrict__ w1s,
    const unsigned short* __restrict__ w2r, const unsigned short* __restrict__ w2s,
    const float* __restrict__ b_rad1, const float* __restrict__ b_sph1,
    const float* __restrict__ b_rad2, const float* __restrict__ b_sph2,
    const unsigned short* __restrict__ qbuf, const unsigned short* __restrict__ kbuf,
    float* __restrict__ out)
{
    __shared__ unsigned short s_a[2 * 64 * 64];   // 16 KB  [path][edge][k] swizzled
    __shared__ unsigned short s_h[64 * 128];      // 16 KB  [edge][hid]    swizzled
    __shared__ unsigned short s_p[64 * 128];      // 16 KB  [edge][c]=q*k  swizzled
    __shared__ float s_alpha[64][4];              // 1 KB

    char* pa = (char*)s_a;
    char* ph = (char*)s_h;
    char* pp = (char*)s_p;

    const int t  = threadIdx.x;
    const int w  = t >> 6;        // wave id == head id
    const int l  = t & 63;
    const int eb = blockIdx.x * BE;

    // ---- Phase P: gather bf16 q,k rows; p = q*k -> bf16 LDS (swizzled) ----
#pragma unroll
    for (int ii = 0; ii < 8; ii++) {
        const int e  = w * 16 + ii * 2 + (l >> 5);
        const int eg = eb + e;
        const int r  = receivers[eg];
        const int s  = senders[eg];
        const int c4 = l & 31;
        const us4 qv = *(const us4*)(qbuf + (size_t)r * 128 + c4 * 4);
        const us4 kv = *(const us4*)(kbuf + (size_t)s * 128 + c4 * 4);
        const float p0 = bf2f(qv[0]) * bf2f(kv[0]);
        const float p1 = bf2f(qv[1]) * bf2f(kv[1]);
        const float p2 = bf2f(qv[2]) * bf2f(kv[2]);
        const float p3 = bf2f(qv[3]) * bf2f(kv[3]);
        const uint2 pv = { cvtpk(p0, p1), cvtpk(p2, p3) };
        *(uint2*)(pp + ((e * 256 + c4 * 8) ^ ((e & 7) << 4))) = pv;
    }

    // ---- Phase A: stage edge_feats & chi_scalar as bf16 (swizzled) ----
#pragma unroll
    for (int ii = 0; ii < 4; ii++) {
        const int idx = t + ii * 256;     // float4 index, 0..1023
        const int r   = idx >> 4;
        const int c4  = idx & 15;
        const float4 a = *(const float4*)(edge_feats + (size_t)(eb + r) * 64 + c4 * 4);
        const float4 b = *(const float4*)(chi_scalar + (size_t)(eb + r) * 64 + c4 * 4);
        const uint2 av = { cvtpk(a.x, a.y), cvtpk(a.z, a.w) };
        const uint2 bv = { cvtpk(b.x, b.y), cvtpk(b.z, b.w) };
        const int off = (r * 128 + c4 * 8) ^ ((r & 7) << 4);
        *(uint2*)(pa + off)        = av;
        *(uint2*)(pa + 8192 + off) = bv;
    }
    __syncthreads();

    f32x4 acc2[2][4];     // [ct][et] final w cols (both paths accumulate here)
#pragma unroll
    for (int ct = 0; ct < 2; ct++)
#pragma unroll
        for (int et = 0; et < 4; et++)
            acc2[ct][et] = (f32x4){0.f, 0.f, 0.f, 0.f};

#pragma unroll
    for (int path = 0; path < 2; path++) {
        const unsigned short* W1p = path ? w1s : w1r;
        const unsigned short* W2p = path ? w2s : w2r;
        const float* b1p = path ? b_sph1 : b_rad1;
        const char*  ab  = pa + path * 8192;

        // ---- Layer 1: wave computes hid cols [w*32, w*32+32) for 64 edges ----
        f32x4 acc1[2][4];
#pragma unroll
        for (int ht = 0; ht < 2; ht++)
#pragma unroll
            for (int et = 0; et < 4; et++)
                acc1[ht][et] = (f32x4){0.f, 0.f, 0.f, 0.f};

#pragma unroll
        for (int kt = 0; kt < 2; kt++) {
            bf16x8 bfrag[4];
#pragma unroll
            for (int et = 0; et < 4; et++) {
                const int e = et * 16 + (l & 15);
                const int k = kt * 32 + (l >> 4) * 8;
                bfrag[et] = *(const bf16x8*)(ab + ((e * 128 + k * 2) ^ ((e & 7) << 4)));
            }
#pragma unroll
            for (int ht = 0; ht < 2; ht++) {
                const int f = kt * 8 + (w * 2 + ht);
                const bf16x8 afrag = *(const bf16x8*)(W1p + (size_t)f * 512 + l * 8);
#pragma unroll
                for (int et = 0; et < 4; et++)
                    acc1[ht][et] = __builtin_amdgcn_mfma_f32_16x16x32_bf16(
                        afrag, bfrag[et], acc1[ht][et], 0, 0, 0);
            }
        }

        // bias + silu -> H  (fast exp + raw rcp; pack via cvt_pk)
#pragma unroll
        for (int ht = 0; ht < 2; ht++) {
            const int hid0 = w * 32 + ht * 16 + (l >> 4) * 4;
            const float4 bv = *(const float4*)(b1p + hid0);
            const float* bvf = (const float*)&bv;
#pragma unroll
            for (int et = 0; et < 4; et++) {
                const int e = et * 16 + (l & 15);
                float s[4];
#pragma unroll
                for (int r = 0; r < 4; r++) {
                    const float v = acc1[ht][et][r] + bvf[r];
                    s[r] = v * __builtin_amdgcn_rcpf(1.0f + __expf(-v));
                }
                const uint2 hv = { cvtpk(s[0], s[1]), cvtpk(s[2], s[3]) };
                *(uint2*)(ph + ((e * 256 + hid0 * 2) ^ ((e & 7) << 4))) = hv;
            }
        }
        __syncthreads();

        // ---- Layer 2: acc2 += W2[cols w*32..+32] @ H  (K = 128) ----
#pragma unroll
        for (int kt = 0; kt < 4; kt++) {
            bf16x8 hfrag[4];
#pragma unroll
            for (int et = 0; et < 4; et++) {
                const int e = et * 16 + (l & 15);
                const int k = kt * 32 + (l >> 4) * 8;
                hfrag[et] = *(const bf16x8*)(ph + ((e * 256 + k * 2) ^ ((e & 7) << 4)));
            }
#pragma unroll
            for (int ct = 0; ct < 2; ct++) {
                const int f = kt * 8 + (w * 2 + ct);
                const bf16x8 afrag = *(const bf16x8*)(W2p + (size_t)f * 512 + l * 8);
#pragma unroll
                for (int et = 0; et < 4; et++)
                    acc2[ct][et] = __builtin_amdgcn_mfma_f32_16x16x32_bf16(
                        afrag, hfrag[et], acc2[ct][et], 0, 0, 0);
            }
        }
        if (path == 0) __syncthreads();   // before next path overwrites s_h
    }

    // ---- Attention: alpha[e][w] = sum_c p[e][c] * (acc2 + b2) ----
    {
        f32x4 b2s[2];
#pragma unroll
        for (int ct = 0; ct < 2; ct++) {
            const int c0 = w * 32 + ct * 16 + (l >> 4) * 4;
            const float4 br = *(const float4*)(b_rad2 + c0);
            const float4 bs = *(const float4*)(b_sph2 + c0);
            b2s[ct] = (f32x4){ br.x + bs.x, br.y + bs.y, br.z + bs.z, br.w + bs.w };
        }
#pragma unroll
        for (int et = 0; et < 4; et++) {
            const int e = et * 16 + (l & 15);
            float vsum = 0.f;
#pragma unroll
            for (int ct = 0; ct < 2; ct++) {
                const int c0 = w * 32 + ct * 16 + (l >> 4) * 4;
                const us4 pv = *(const us4*)(pp + ((e * 256 + c0 * 2) ^ ((e & 7) << 4)));
#pragma unroll
                for (int r = 0; r < 4; r++)
                    vsum = fmaf(bf2f(pv[r]), acc2[ct][et][r] + b2s[ct][r], vsum);
            }
            vsum += __shfl_xor(vsum, 16, 64);
            vsum += __shfl_xor(vsum, 32, 64);
            if (l < 16) {
                // 1/sqrt(32) * 1/32
                s_alpha[et * 16 + l][w] = vsum * cutoffs[eb + et * 16 + l]
                                        * 0.005524271728019903f;
            }
        }
    }
    __syncthreads();

    // ---- Scatter (coalesced): 4 adjacent lanes cover one edge's 16 comps ----
    {
        const int e   = t >> 2;
        const int c0q = t & 3;
        const int eg  = eb + e;
        const int rn  = receivers[eg];
        const float4 sh = *(const float4*)(edge_sh + (size_t)eg * 16 + c0q * 4);
        const float* shf = (const float*)&sh;
#pragma unroll
        for (int j = 0; j < 4; j++) {
            const int comp = c0q * 4 + j;
            const int head = (comp == 0) ? 0 : (comp < 4) ? 1 : (comp < 9) ? 2 : 3;
            atomicAdd(&out[(size_t)rn * 16 + comp], shf[j] * s_alpha[e][head]);
        }
    }
}

// ---------------------------------------------------------------------------
extern "C" void kernel_launch(void* const* d_in, const int* in_sizes, int n_in,
                              void* d_out, int out_size, void* d_ws, size_t ws_size,
                              hipStream_t stream)
{
    const float* edge_sh    = (const float*)d_in[0];
    const float* node_feats = (const float*)d_in[1];
    const float* edge_feats = (const float*)d_in[2];
    const float* chi_scalar = (const float*)d_in[3];
    const float* cutoffs    = (const float*)d_in[4];
    const int*   senders    = (const int*)d_in[5];
    const int*   receivers  = (const int*)d_in[6];
    const float* W_rad1 = (const float*)d_in[7];
    const float* b_rad1 = (const float*)d_in[8];
    const float* W_rad2 = (const float*)d_in[9];
    const float* b_rad2 = (const float*)d_in[10];
    const float* W_sph1 = (const float*)d_in[11];
    const float* b_sph1 = (const float*)d_in[12];
    const float* W_sph2 = (const float*)d_in[13];
    const float* b_sph2 = (const float*)d_in[14];
    const float* Wq     = (const float*)d_in[15];
    const float* Wk     = (const float*)d_in[16];

    float* out = (float*)d_out;
    unsigned short* qbuf = (unsigned short*)d_ws;        // [N,128] bf16
    unsigned short* kbuf = qbuf + (size_t)NNODES * DDIM; // [N,128] bf16
    unsigned short* w1r  = kbuf + (size_t)NNODES * DDIM;
    unsigned short* w1s  = w1r + 16 * 512;
    unsigned short* w2r  = w1s + 16 * 512;
    unsigned short* w2s  = w2r + 32 * 512;

    hipMemsetAsync(out, 0, (size_t)out_size * sizeof(float), stream);

    pack_weights<<<16, 256, 0, stream>>>(W_rad1, w1r);
    pack_weights<<<16, 256, 0, stream>>>(W_sph1, w1s);
    pack_weights<<<32, 256, 0, stream>>>(W_rad2, w2r);
    pack_weights<<<32, 256, 0, stream>>>(W_sph2, w2s);

    qk_proj_kernel<<<NNODES / TN, 256, 0, stream>>>(node_feats, Wq, Wk, qbuf, kbuf);

    edge_kernel<<<NEDGES / BE, 256, 0, stream>>>(
        edge_sh, cutoffs, senders, receivers, edge_feats, chi_scalar,
        w1r, w1s, w2r, w2s, b_rad1, b_sph1, b_rad2, b_sph2,
        qbuf, kbuf, out);
}